// Round 2
// baseline (679.933 us; speedup 1.0000x reference)
//
#include <hip/hip_runtime.h>
#include <hip/hip_bf16.h>

// Problem constants
#define S_LEN 4096
#define BATCH 16
#define DIM 1024
#define HDIM 512
#define LPOOL 32
#define NCOL (BATCH * DIM)      // 16384
#define NCOL4 (NCOL / 4)        // 4096
#define SCHUNK 64               // s-chunks for colsum
#define ROWS_PER_CHUNK (S_LEN / SCHUNK) // 64
#define LN_EPS 1e-5f

__device__ __forceinline__ float gelu_exact(float x) {
    return 0.5f * x * (1.0f + erff(x * 0.70710678118654752440f));
}

__device__ __forceinline__ float wave_reduce_sum(float v) {
    #pragma unroll
    for (int off = 32; off > 0; off >>= 1) v += __shfl_down(v, off);
    return v; // valid on lane 0
}

// ---------------------------------------------------------------------------
// K1: partial column sums of features: part[sc][c] = sum over 64 s rows
// grid (16 colblocks, 64 schunks), block 256 (each thread one float4 column grp)
__global__ void __launch_bounds__(256) k_colsum(const float* __restrict__ f,
                                                float* __restrict__ part) {
    int cb = blockIdx.x;          // 0..15
    int sc = blockIdx.y;          // 0..63
    int t  = threadIdx.x;
    int c4 = cb * 256 + t;        // float4 column index, < 4096
    const float4* f4 = (const float4*)f;
    float4 acc = make_float4(0.f, 0.f, 0.f, 0.f);
    int base = sc * ROWS_PER_CHUNK;
    #pragma unroll 4
    for (int i = 0; i < ROWS_PER_CHUNK; ++i) {
        float4 v = f4[(size_t)(base + i) * NCOL4 + c4];
        acc.x += v.x; acc.y += v.y; acc.z += v.z; acc.w += v.w;
    }
    ((float4*)part)[(size_t)sc * NCOL4 + c4] = acc;
}

// K2: context[c] = sum_k part[k][c] / S
__global__ void __launch_bounds__(256) k_ctx_reduce(const float* __restrict__ part,
                                                    float* __restrict__ context) {
    int c = blockIdx.x * 256 + threadIdx.x; // < 16384
    float s = 0.f;
    #pragma unroll 8
    for (int k = 0; k < SCHUNK; ++k) s += part[(size_t)k * NCOL + c];
    context[c] = s * (1.0f / (float)S_LEN);
}

// KT: transpose first-half columns of w_rs1 (512 x 2048) -> wT (1024 x 512)
__global__ void k_transpose(const float* __restrict__ w, float* __restrict__ wT) {
    __shared__ float tile[32][33];
    int jt = blockIdx.x * 32;     // 16 blocks over j (512)
    int dt = blockIdx.y * 32;     // 32 blocks over d (1024)
    int tx = threadIdx.x & 31, ty = threadIdx.x >> 5; // 32 x 8
    #pragma unroll
    for (int i = 0; i < 32; i += 8)
        tile[ty + i][tx] = w[(size_t)(jt + ty + i) * 2048 + dt + tx];
    __syncthreads();
    #pragma unroll
    for (int i = 0; i < 32; i += 8)
        wT[(size_t)(dt + ty + i) * 512 + jt + tx] = tile[tx][ty + i];
}

// K3: sp_h[b][j] = gelu(ctx[b] . w_sp1[j] + b_sp1[j]); one wave per output
// grid 2048 x 256 (8192 waves)
__global__ void k_sph(const float* __restrict__ ctx, const float* __restrict__ w1,
                      const float* __restrict__ b1, float* __restrict__ sph) {
    int wid = blockIdx.x * 4 + (threadIdx.x >> 6);
    int lane = threadIdx.x & 63;
    int b = wid >> 9;          // / 512
    int j = wid & 511;
    const float4* x4 = (const float4*)(ctx + (size_t)b * DIM);
    const float4* w4 = (const float4*)(w1 + (size_t)j * DIM);
    float s = 0.f;
    #pragma unroll
    for (int i = 0; i < 4; ++i) {
        float4 a = x4[lane + i * 64], w = w4[lane + i * 64];
        s += a.x * w.x + a.y * w.y + a.z * w.z + a.w * w.w;
    }
    s = wave_reduce_sum(s);
    if (lane == 0) sph[b * HDIM + j] = gelu_exact(s + b1[j]);
}

// K4: span weights: softmax over 3 of sp_h[b] . w_sp2[k] + b_sp2[k]
// grid 16, block 64
__global__ void k_span(const float* __restrict__ sph, const float* __restrict__ w2,
                       const float* __restrict__ b2, float* __restrict__ spanw) {
    int b = blockIdx.x, lane = threadIdx.x;
    float vals[3];
    #pragma unroll
    for (int k = 0; k < 3; ++k) {
        const float4* x4 = (const float4*)(sph + (size_t)b * HDIM);
        const float4* w4 = (const float4*)(w2 + (size_t)k * HDIM);
        float s = 0.f;
        #pragma unroll
        for (int i = 0; i < 2; ++i) {
            float4 a = x4[lane + i * 64], w = w4[lane + i * 64];
            s += a.x * w.x + a.y * w.y + a.z * w.z + a.w * w.w;
        }
        s = wave_reduce_sum(s);
        vals[k] = s;
    }
    if (lane == 0) {
        float l0 = vals[0] + b2[0], l1 = vals[1] + b2[1], l2 = vals[2] + b2[2];
        float m = fmaxf(l0, fmaxf(l1, l2));
        float e0 = expf(l0 - m), e1 = expf(l1 - m), e2 = expf(l2 - m);
        float inv = 1.0f / (e0 + e1 + e2);
        spanw[b * 3 + 0] = e0 * inv;
        spanw[b * 3 + 1] = e1 * inv;
        spanw[b * 3 + 2] = e2 * inv;
    }
}

// K5: ctx_part[b][j] = ctx[b] . w_rs1[j, 1024:2048] + b_rs1[j]
// grid 2048 x 256
__global__ void k_ctxpart(const float* __restrict__ ctx, const float* __restrict__ wrs1,
                          const float* __restrict__ brs1, float* __restrict__ cpart) {
    int wid = blockIdx.x * 4 + (threadIdx.x >> 6);
    int lane = threadIdx.x & 63;
    int b = wid >> 9;
    int j = wid & 511;
    const float4* x4 = (const float4*)(ctx + (size_t)b * DIM);
    const float4* w4 = (const float4*)(wrs1 + (size_t)j * 2048 + 1024);
    float s = 0.f;
    #pragma unroll
    for (int i = 0; i < 4; ++i) {
        float4 a = x4[lane + i * 64], w = w4[lane + i * 64];
        s += a.x * w.x + a.y * w.y + a.z * w.z + a.w * w.w;
    }
    s = wave_reduce_sum(s);
    if (lane == 0) cpart[b * HDIM + j] = s + brs1[j];
}

// K6: h[p][l][b][j] = gelu(hist(p,l,b) . w_rs1[j,0:1024] + ctx_part[b][j])
// grid (64 = p*32+l, 4 = j-quarter), block 256; hist row staged in LDS
__global__ void __launch_bounds__(256) k_poolh(const float* __restrict__ feat,
                                               const float* __restrict__ wT,
                                               const float* __restrict__ cpart,
                                               float* __restrict__ hws) {
    int pl = blockIdx.x;
    int p = pl >> 5, l = pl & 31;
    int jq = blockIdx.y;
    int s = (p == 0) ? (S_LEN - LPOOL + l) : (l * (S_LEN / 32));
    __shared__ float hist[BATCH * DIM]; // 64 KiB
    const float4* src4 = (const float4*)(feat + (size_t)s * NCOL);
    float4* h4 = (float4*)hist;
    #pragma unroll
    for (int i = 0; i < 16; ++i) h4[threadIdx.x + i * 256] = src4[threadIdx.x + i * 256];
    __syncthreads();
    int lane = threadIdx.x & 63;
    int b0 = (threadIdx.x >> 6) * 4;
    int j0 = jq * 128 + lane * 2;
    float acc[4][2];
    #pragma unroll
    for (int k = 0; k < 4; ++k) {
        acc[k][0] = cpart[(b0 + k) * HDIM + j0];
        acc[k][1] = cpart[(b0 + k) * HDIM + j0 + 1];
    }
    #pragma unroll 4
    for (int d = 0; d < DIM; ++d) {
        float2 w = *(const float2*)&wT[(size_t)d * HDIM + j0];
        #pragma unroll
        for (int k = 0; k < 4; ++k) {
            float h = hist[(b0 + k) * DIM + d];
            acc[k][0] += h * w.x;
            acc[k][1] += h * w.y;
        }
    }
    #pragma unroll
    for (int k = 0; k < 4; ++k) {
        int b = b0 + k;
        float2 o = make_float2(gelu_exact(acc[k][0]), gelu_exact(acc[k][1]));
        *(float2*)&hws[(((size_t)pl) * BATCH + b) * HDIM + j0] = o;
    }
}

// K7: scores -> softmax(decay) -> pooled feat -> combined (scaled by span wt)
// grid 32 (p*16+b), block 256
__global__ void k_pool_finish(const float* __restrict__ feat, const float* __restrict__ hws,
                              const float* __restrict__ wrs2, const float* __restrict__ brs2,
                              const float* __restrict__ spanw, const float* __restrict__ dl,
                              const float* __restrict__ dg, float* __restrict__ combined) {
    int p = blockIdx.x >> 4, b = blockIdx.x & 15;
    int t = threadIdx.x, lane = t & 63, w = t >> 6;
    __shared__ float sc[LPOOL];
    __shared__ float wl[LPOOL];
    for (int li = w; li < LPOOL; li += 4) {
        const float4* h4 = (const float4*)(hws + (((size_t)(p * LPOOL + li)) * BATCH + b) * HDIM);
        const float4* w4 = (const float4*)wrs2;
        float s = 0.f;
        #pragma unroll
        for (int i = 0; i < 2; ++i) {
            float4 a = h4[lane + i * 64], ww = w4[lane + i * 64];
            s += a.x * ww.x + a.y * ww.y + a.z * ww.z + a.w * ww.w;
        }
        s = wave_reduce_sum(s);
        if (lane == 0) sc[li] = s + brs2[0];
    }
    __syncthreads();
    if (t == 0) {
        float decay = (p == 0) ? dl[0] : dg[0];
        float lg[LPOOL];
        float m = -1e30f;
        #pragma unroll
        for (int li = 0; li < LPOOL; ++li) {
            lg[li] = sc[li] + logf(powf(decay, (float)(LPOOL - 1 - li)) + 1e-8f);
            m = fmaxf(m, lg[li]);
        }
        float sum = 0.f;
        #pragma unroll
        for (int li = 0; li < LPOOL; ++li) { lg[li] = expf(lg[li] - m); sum += lg[li]; }
        float inv = 1.0f / sum;
        #pragma unroll
        for (int li = 0; li < LPOOL; ++li) wl[li] = lg[li] * inv;
    }
    __syncthreads();
    float sw = spanw[b * 3 + 1 + p];
    float4 acc = make_float4(0.f, 0.f, 0.f, 0.f);
    for (int li = 0; li < LPOOL; ++li) {
        int s_idx = (p == 0) ? (S_LEN - LPOOL + li) : (li * (S_LEN / 32));
        float4 v = ((const float4*)(feat + ((size_t)s_idx * BATCH + b) * DIM))[t];
        float wv = wl[li];
        acc.x += wv * v.x; acc.y += wv * v.y; acc.z += wv * v.z; acc.w += wv * v.w;
    }
    acc.x *= sw; acc.y *= sw; acc.z *= sw; acc.w *= sw;
    ((float4*)(combined + (size_t)b * 2048 + p * DIM))[t] = acc;
}

// K8: ffout[b][j] = gelu(combined[b] . w_ff[j] + b_ff[j]); K=2048, one wave/out
// grid 4096 x 256
__global__ void k_ff(const float* __restrict__ comb, const float* __restrict__ wff,
                     const float* __restrict__ bff, float* __restrict__ ffout) {
    int wid = blockIdx.x * 4 + (threadIdx.x >> 6);
    int lane = threadIdx.x & 63;
    int b = wid >> 10, j = wid & 1023;
    const float4* x4 = (const float4*)(comb + (size_t)b * 2048);
    const float4* w4 = (const float4*)(wff + (size_t)j * 2048);
    float s = 0.f;
    #pragma unroll
    for (int i = 0; i < 8; ++i) {
        float4 a = x4[lane + i * 64], w = w4[lane + i * 64];
        s += a.x * w.x + a.y * w.y + a.z * w.z + a.w * w.w;
    }
    s = wave_reduce_sum(s);
    if (lane == 0) ffout[b * DIM + j] = gelu_exact(s + bff[j]);
}

__device__ __forceinline__ float2 block_sum2(float a, float bsum) {
    __shared__ float sa[4], sb[4];
    int lane = threadIdx.x & 63, w = threadIdx.x >> 6;
    #pragma unroll
    for (int off = 32; off > 0; off >>= 1) {
        a += __shfl_down(a, off);
        bsum += __shfl_down(bsum, off);
    }
    if (lane == 0) { sa[w] = a; sb[w] = bsum; }
    __syncthreads();
    float ta = sa[0] + sa[1] + sa[2] + sa[3];
    float tb = sb[0] + sb[1] + sb[2] + sb[3];
    return make_float2(ta, tb);
}

// K9a: fused[b] = layernorm(ffout[b]) * ln_ff_g + ln_ff_b ; grid 16, block 256
__global__ void k_ln_ff(const float* __restrict__ ffout, const float* __restrict__ g,
                        const float* __restrict__ bb, float* __restrict__ fused) {
    int b = blockIdx.x, t = threadIdx.x;
    float4 y = ((const float4*)(ffout + (size_t)b * DIM))[t];
    float s = y.x + y.y + y.z + y.w;
    float ss = y.x * y.x + y.y * y.y + y.z * y.z + y.w * y.w;
    float2 tot = block_sum2(s, ss);
    float mu = tot.x * (1.0f / DIM);
    float var = tot.y * (1.0f / DIM) - mu * mu;
    float rs = rsqrtf(var + LN_EPS);
    float4 g4 = ((const float4*)g)[t], b4 = ((const float4*)bb)[t];
    float4 o;
    o.x = (y.x - mu) * rs * g4.x + b4.x;
    o.y = (y.y - mu) * rs * g4.y + b4.y;
    o.z = (y.z - mu) * rs * g4.z + b4.z;
    o.w = (y.w - mu) * rs * g4.w + b4.w;
    ((float4*)(fused + (size_t)b * DIM))[t] = o;
}

// K9b: fg[b][j] = fused[b][j] * sigmoid(fused[b] . w_gate[j] + b_gate[j])
// grid 4096 x 256, one wave per output, K=1024
__global__ void k_gate(const float* __restrict__ fused, const float* __restrict__ wg,
                       const float* __restrict__ bg, float* __restrict__ fg) {
    int wid = blockIdx.x * 4 + (threadIdx.x >> 6);
    int lane = threadIdx.x & 63;
    int b = wid >> 10, j = wid & 1023;
    const float4* x4 = (const float4*)(fused + (size_t)b * DIM);
    const float4* w4 = (const float4*)(wg + (size_t)j * DIM);
    float s = 0.f;
    #pragma unroll
    for (int i = 0; i < 4; ++i) {
        float4 a = x4[lane + i * 64], w = w4[lane + i * 64];
        s += a.x * w.x + a.y * w.y + a.z * w.z + a.w * w.w;
    }
    s = wave_reduce_sum(s);
    if (lane == 0) {
        float gv = 1.0f / (1.0f + expf(-(s + bg[j])));
        fg[b * DIM + j] = fused[b * DIM + j] * gv;
    }
}

// K10: out[s,b,:] = layernorm(fg[b] + features[s,b]) * ln_g + ln_b; attn fill
// grid 65536 (s*16+b), block 256
__global__ void __launch_bounds__(256) k_final(const float* __restrict__ feat,
                                               const float* __restrict__ fg,
                                               const float* __restrict__ g,
                                               const float* __restrict__ bb,
                                               float* __restrict__ out,
                                               float* __restrict__ attn) {
    int r = blockIdx.x;  // s*16+b
    int b = r & 15;
    int t = threadIdx.x;
    float4 x = ((const float4*)feat)[(size_t)r * 256 + t];
    float4 f4 = ((const float4*)(fg + (size_t)b * DIM))[t];
    float4 y;
    y.x = x.x + f4.x; y.y = x.y + f4.y; y.z = x.z + f4.z; y.w = x.w + f4.w;
    float s = y.x + y.y + y.z + y.w;
    float ss = y.x * y.x + y.y * y.y + y.z * y.z + y.w * y.w;
    float2 tot = block_sum2(s, ss);
    float mu = tot.x * (1.0f / DIM);
    float var = tot.y * (1.0f / DIM) - mu * mu;
    float rs = rsqrtf(var + LN_EPS);
    float4 g4 = ((const float4*)g)[t], bb4 = ((const float4*)bb)[t];
    float4 o;
    o.x = (y.x - mu) * rs * g4.x + bb4.x;
    o.y = (y.y - mu) * rs * g4.y + bb4.y;
    o.z = (y.z - mu) * rs * g4.z + bb4.z;
    o.w = (y.w - mu) * rs * g4.w + bb4.w;
    ((float4*)out)[(size_t)r * 256 + t] = o;
    if (t == 0) attn[r] = 1.0f / (float)S_LEN;
}

extern "C" void kernel_launch(void* const* d_in, const int* in_sizes, int n_in,
                              void* d_out, int out_size, void* d_ws, size_t ws_size,
                              hipStream_t stream) {
    const float* feat    = (const float*)d_in[0];
    const float* w_sp1   = (const float*)d_in[1];
    const float* b_sp1   = (const float*)d_in[2];
    const float* w_sp2   = (const float*)d_in[3];
    const float* b_sp2   = (const float*)d_in[4];
    const float* w_rs1   = (const float*)d_in[5];
    const float* b_rs1   = (const float*)d_in[6];
    const float* w_rs2   = (const float*)d_in[7];
    const float* b_rs2   = (const float*)d_in[8];
    const float* dl      = (const float*)d_in[9];
    const float* dg      = (const float*)d_in[10];
    const float* w_ff    = (const float*)d_in[11];
    const float* b_ff    = (const float*)d_in[12];
    const float* ln_ff_g = (const float*)d_in[13];
    const float* ln_ff_b = (const float*)d_in[14];
    const float* w_gate  = (const float*)d_in[15];
    const float* b_gate  = (const float*)d_in[16];
    const float* ln_g    = (const float*)d_in[17];
    const float* ln_b    = (const float*)d_in[18];

    float* out  = (float*)d_out;
    float* attn = out + (size_t)S_LEN * BATCH * DIM;

    float* ws = (float*)d_ws;
    // region A (reused): part (64*16384 = 1,048,576 floats), later wT + hws
    float* part     = ws;
    float* wT       = ws;               // 524288 floats, written after part consumed
    float* hws      = ws + 524288;      // 524288 floats
    float* context  = ws + 1048576;     // 16384
    float* sph      = context + 16384;  // 8192
    float* spanw    = sph + 8192;       // 64 (48 used)
    float* cpart    = spanw + 64;       // 8192
    float* combined = cpart + 8192;     // 32768
    float* ffout    = combined + 32768; // 16384
    float* fusedv   = ffout + 16384;    // 16384
    float* fgv      = fusedv + 16384;   // 16384

    k_colsum<<<dim3(16, 64), 256, 0, stream>>>(feat, part);
    k_ctx_reduce<<<64, 256, 0, stream>>>(part, context);
    k_transpose<<<dim3(16, 32), 256, 0, stream>>>(w_rs1, wT); // after part consumed
    k_sph<<<2048, 256, 0, stream>>>(context, w_sp1, b_sp1, sph);
    k_span<<<16, 64, 0, stream>>>(sph, w_sp2, b_sp2, spanw);
    k_ctxpart<<<2048, 256, 0, stream>>>(context, w_rs1, b_rs1, cpart);
    k_poolh<<<dim3(64, 4), 256, 0, stream>>>(feat, wT, cpart, hws);
    k_pool_finish<<<32, 256, 0, stream>>>(feat, hws, w_rs2, b_rs2, spanw, dl, dg, combined);
    k_ff<<<4096, 256, 0, stream>>>(combined, w_ff, b_ff, ffout);
    k_ln_ff<<<16, 256, 0, stream>>>(ffout, ln_ff_g, ln_ff_b, fusedv);
    k_gate<<<4096, 256, 0, stream>>>(fusedv, w_gate, b_gate, fgv);
    k_final<<<65536, 256, 0, stream>>>(feat, fgv, ln_g, ln_b, out, attn);
}